// Round 1
// baseline (4455.796 us; speedup 1.0000x reference)
//
#include <hip/hip_runtime.h>
#include <stdint.h>

#define BATCH 8
#define K 65536
#define CFEAT 128
#define NPROP 1024
#define M 16            // workgroups per batch
#define T 256           // threads per WG
#define PTS (K / M)     // 4096 points per WG
#define PPT (PTS / T)   // 16 points per thread

// d_out layout (float32): new_xyz (B,N,3) | new_features (B,C,N) | inds (B,N) as float
#define OUT_FEAT (BATCH * NPROP * 3)                       // 24576
#define OUT_INDS (BATCH * NPROP * 3 + BATCH * CFEAT * NPROP) // 1073152

// ws layout: slotA[2][BATCH][M], slotB[2][BATCH][M], slotC[2][BATCH][M] (ull each)
#define SLOTS_PER (2 * BATCH * M)   // 256 ulls per array

__global__ __launch_bounds__(256) void fps_init(unsigned long long* ws) {
    // zero the tag-carrying slotA region so stale tags from a previous graph
    // replay can never match a live iteration tag (t starts at 1, tag 0 unused)
    ws[threadIdx.x] = 0ull;
}

__global__ __launch_bounds__(T) void fps_kernel(const float* __restrict__ xyz,
                                                float* __restrict__ out,
                                                unsigned long long* __restrict__ ws) {
    // batch = blockIdx & 7 so one batch's 16 WGs land on one XCD (round-robin
    // blockIdx->XCD) -> spin traffic stays L2-local where possible.
    const int b = blockIdx.x & 7;
    const int w = blockIdx.x >> 3;
    const int tid = threadIdx.x;
    const float* xb = xyz + (size_t)b * (K * 3);
    const int base = w * PTS;

    unsigned long long* slotA = ws;                  // key+tag
    unsigned long long* slotB = ws + SLOTS_PER;      // (x,y)
    unsigned long long* slotC = ws + 2 * SLOTS_PER;  // (z)

    __shared__ float sx[PTS], sy[PTS], sz[PTS];      // 48 KB: winner-coord recovery
    __shared__ unsigned long long s_wkey[T / 64];
    __shared__ float s_wx[T / 64], s_wy[T / 64], s_wz[T / 64];
    __shared__ float s_qx, s_qy, s_qz;

    // stage this WG's slice into registers (hot loop) + LDS (coord recovery)
    float px[PPT], py[PPT], pz[PPT], dist[PPT];
#pragma unroll
    for (int j = 0; j < PPT; ++j) {
        int l = j * T + tid;
        int g = base + l;
        px[j] = xb[3 * g];
        py[j] = xb[3 * g + 1];
        pz[j] = xb[3 * g + 2];
        sx[l] = px[j]; sy[l] = py[j]; sz[l] = pz[j];
        dist[j] = 1e10f;
    }
    // first picked point = global index 0
    float qx = xb[0], qy = xb[1], qz = xb[2];
    if (w == 0 && tid == 0) out[OUT_INDS + b * NPROP] = 0.0f;
    __syncthreads();

    for (int t = 1; t < NPROP; ++t) {
        // ---- local distance update + per-thread argmax (bit-exact vs numpy:
        // no FMA contraction, (dx2+dy2)+dz2 order, first-max tie-break) ----
        unsigned long long best = 0ull;
#pragma unroll
        for (int j = 0; j < PPT; ++j) {
            float dx = __fsub_rn(px[j], qx);
            float dy = __fsub_rn(py[j], qy);
            float dz = __fsub_rn(pz[j], qz);
            float d = __fadd_rn(__fadd_rn(__fmul_rn(dx, dx), __fmul_rn(dy, dy)),
                                __fmul_rn(dz, dz));
            float nd = fminf(dist[j], d);
            dist[j] = nd;
            unsigned int l = (unsigned int)(j * T + tid);
            unsigned long long key =
                ((unsigned long long)__float_as_uint(nd) << 32) | (unsigned int)(~l);
            best = (key > best) ? key : best;
        }
        // ---- wave (64-lane) max-reduce ----
#pragma unroll
        for (int off = 32; off >= 1; off >>= 1) {
            unsigned long long o = __shfl_down(best, (unsigned)off, 64);
            best = (o > best) ? o : best;
        }
        int wv = tid >> 6;
        if ((tid & 63) == 0) {
            unsigned int l = ~((unsigned int)best);   // local idx of wave best
            s_wkey[wv] = best;
            s_wx[wv] = sx[l]; s_wy[wv] = sy[l]; s_wz[wv] = sz[l];
        }
        __syncthreads();   // S1

        const int par = t & 1;
        unsigned long long* sA = slotA + ((par * BATCH + b) * M);
        unsigned long long* sB = slotB + ((par * BATCH + b) * M);
        unsigned long long* sC = slotC + ((par * BATCH + b) * M);

        if (tid == 0) {
            // block-level winner across the 4 waves
            unsigned long long kb = s_wkey[0];
            float bx = s_wx[0], by = s_wy[0], bz = s_wz[0];
#pragma unroll
            for (int i = 1; i < T / 64; ++i) {
                if (s_wkey[i] > kb) { kb = s_wkey[i]; bx = s_wx[i]; by = s_wy[i]; bz = s_wz[i]; }
            }
            unsigned int lidx = ~((unsigned int)kb);
            unsigned int g = (unsigned int)base + lidx;        // global idx <= 65535
            unsigned int db = (unsigned int)(kb >> 32);        // dist bits
            unsigned long long pb =
                ((unsigned long long)__float_as_uint(by) << 32) | __float_as_uint(bx);
            unsigned long long pc = (unsigned long long)__float_as_uint(bz);
            __hip_atomic_store(&sB[w], pb, __ATOMIC_RELAXED, __HIP_MEMORY_SCOPE_AGENT);
            __hip_atomic_store(&sC[w], pc, __ATOMIC_RELAXED, __HIP_MEMORY_SCOPE_AGENT);
            // key: dist | (0xFFFF - gidx) [smaller idx wins ties] | tag=t (freshness)
            unsigned long long ka = ((unsigned long long)db << 32) |
                                    ((unsigned long long)(0xFFFFu - g) << 16) |
                                    (unsigned long long)(unsigned int)t;
            __hip_atomic_store(&sA[w], ka, __ATOMIC_RELEASE, __HIP_MEMORY_SCOPE_AGENT);
        }

        // ---- spin-exchange: lanes 0..15 each watch one WG's slot; the tagged
        // release-store IS the barrier (single visibility round trip) ----
        if (tid < M) {
            unsigned long long k;
            do {
                k = __hip_atomic_load(&sA[tid], __ATOMIC_ACQUIRE, __HIP_MEMORY_SCOPE_AGENT);
            } while ((unsigned short)k != (unsigned short)t);
            unsigned long long pb =
                __hip_atomic_load(&sB[tid], __ATOMIC_RELAXED, __HIP_MEMORY_SCOPE_AGENT);
            unsigned long long pc =
                __hip_atomic_load(&sC[tid], __ATOMIC_RELAXED, __HIP_MEMORY_SCOPE_AGENT);
#pragma unroll
            for (int off = 8; off >= 1; off >>= 1) {
                unsigned long long k2 = __shfl_down(k, (unsigned)off, 64);
                unsigned long long b2 = __shfl_down(pb, (unsigned)off, 64);
                unsigned long long c2 = __shfl_down(pc, (unsigned)off, 64);
                if (k2 > k) { k = k2; pb = b2; pc = c2; }
            }
            if (tid == 0) {
                int far = 0xFFFF - (int)((k >> 16) & 0xFFFFu);
                s_qx = __uint_as_float((unsigned int)pb);
                s_qy = __uint_as_float((unsigned int)(pb >> 32));
                s_qz = __uint_as_float((unsigned int)pc);
                if (w == 0) out[OUT_INDS + b * NPROP + t] = (float)far;
            }
        }
        __syncthreads();   // S2
        qx = s_qx; qy = s_qy; qz = s_qz;
    }
}

__global__ __launch_bounds__(256) void gather_kernel(const float* __restrict__ xyz,
                                                     const float* __restrict__ feat,
                                                     float* __restrict__ out) {
    int gid = blockIdx.x * 256 + threadIdx.x;   // covers B*C*N = 1,048,576
    int n = gid & (NPROP - 1);
    int b = gid >> 17;                          // C*N = 2^17
    int c = (gid >> 10) & (CFEAT - 1);
    int ind = (int)out[OUT_INDS + (b << 10) + n];   // float inds, exact < 2^24
    out[OUT_FEAT + gid] = feat[(((size_t)b * CFEAT + c) << 16) + (size_t)ind];
    if (gid < BATCH * NPROP) {
        int b2 = gid >> 10;
        int ind2 = (int)out[OUT_INDS + gid];
        const float* s = xyz + ((size_t)b2 * K + (size_t)ind2) * 3;
        float a0 = s[0], a1 = s[1], a2 = s[2];
        out[gid * 3 + 0] = a0;
        out[gid * 3 + 1] = a1;
        out[gid * 3 + 2] = a2;
    }
}

extern "C" void kernel_launch(void* const* d_in, const int* in_sizes, int n_in,
                              void* d_out, int out_size, void* d_ws, size_t ws_size,
                              hipStream_t stream) {
    const float* xyz = (const float*)d_in[0];
    const float* feat = (const float*)d_in[1];
    float* out = (float*)d_out;
    unsigned long long* ws = (unsigned long long*)d_ws;

    hipLaunchKernelGGL(fps_init, dim3(1), dim3(256), 0, stream, ws);
    hipLaunchKernelGGL(fps_kernel, dim3(BATCH * M), dim3(T), 0, stream,
                       xyz, out, ws);
    hipLaunchKernelGGL(gather_kernel, dim3(BATCH * CFEAT * NPROP / 256), dim3(256),
                       0, stream, xyz, feat, out);
}

// Round 2
// 3963.174 us; speedup vs baseline: 1.1243x; 1.1243x over previous
//
#include <hip/hip_runtime.h>
#include <stdint.h>

#define BATCH 8
#define K 65536
#define CFEAT 128
#define NPROP 1024
#define M 16            // workgroups per batch
#define T 256           // threads per WG
#define PTS (K / M)     // 4096 points per WG
#define PPT (PTS / T)   // 16 points per thread

// d_out layout (float32): new_xyz (B,N,3) | new_features (B,C,N) | inds (B,N) as float
#define OUT_FEAT (BATCH * NPROP * 3)                         // 24576
#define OUT_INDS (BATCH * NPROP * 3 + BATCH * CFEAT * NPROP) // 1073152

// ws layout: slot[2][BATCH][M] blocks, each padded to its OWN 64B cacheline
// (8 ulls). Within a block: [0]=key{dist|0xFFFF-g|tag}, [1]={tag<<32|z},
// [2]={tag<<32|x}, [3]={tag<<32|y}. Padding kills the 16-writer same-line
// ownership serialization that cost ~9600 cyc/iter in round 1.
#define SLOT_STRIDE 8
#define WS_ULLS (2 * BATCH * M * SLOT_STRIDE)   // 2048 ulls = 16 KB

__global__ __launch_bounds__(256) void fps_init(unsigned long long* ws) {
    int i = blockIdx.x * 256 + threadIdx.x;
    if (i < WS_ULLS) ws[i] = 0ull;   // tag 0 never matches t in [1,1023]
}

__global__ __launch_bounds__(T) void fps_kernel(const float* __restrict__ xyz,
                                                float* __restrict__ out,
                                                unsigned long long* __restrict__ ws) {
    const int b = blockIdx.x & 7;   // batch's 16 WGs round-robin onto one XCD
    const int w = blockIdx.x >> 3;
    const int tid = threadIdx.x;
    const float* xb = xyz + (size_t)b * (K * 3);
    const int base = w * PTS;

    __shared__ float sx[PTS], sy[PTS], sz[PTS];   // 48 KB: winner-coord recovery
    __shared__ unsigned long long s_wkey[T / 64];
    __shared__ float s_wx[T / 64], s_wy[T / 64], s_wz[T / 64];
    __shared__ float s_qx, s_qy, s_qz;

    float px[PPT], py[PPT], pz[PPT], dist[PPT];
#pragma unroll
    for (int j = 0; j < PPT; ++j) {
        int l = j * T + tid;
        int g = base + l;
        px[j] = xb[3 * g];
        py[j] = xb[3 * g + 1];
        pz[j] = xb[3 * g + 2];
        sx[l] = px[j]; sy[l] = py[j]; sz[l] = pz[j];
        dist[j] = 1e10f;
    }
    float qx = xb[0], qy = xb[1], qz = xb[2];
    if (w == 0 && tid == 0) out[OUT_INDS + b * NPROP] = 0.0f;
    __syncthreads();

    for (int t = 1; t < NPROP; ++t) {
        // ---- local distance update + per-thread argmax (bit-exact vs numpy:
        // no FMA contraction, (dx2+dy2)+dz2 order, first-max tie-break) ----
        unsigned long long best = 0ull;
#pragma unroll
        for (int j = 0; j < PPT; ++j) {
            float dx = __fsub_rn(px[j], qx);
            float dy = __fsub_rn(py[j], qy);
            float dz = __fsub_rn(pz[j], qz);
            float d = __fadd_rn(__fadd_rn(__fmul_rn(dx, dx), __fmul_rn(dy, dy)),
                                __fmul_rn(dz, dz));
            float nd = fminf(dist[j], d);
            dist[j] = nd;
            unsigned int l = (unsigned int)(j * T + tid);
            unsigned long long key =
                ((unsigned long long)__float_as_uint(nd) << 32) | (unsigned int)(~l);
            best = (key > best) ? key : best;
        }
#pragma unroll
        for (int off = 32; off >= 1; off >>= 1) {
            unsigned long long o = __shfl_down(best, (unsigned)off, 64);
            best = (o > best) ? o : best;
        }
        int wv = tid >> 6;
        if ((tid & 63) == 0) {
            unsigned int l = ~((unsigned int)best);
            s_wkey[wv] = best;
            s_wx[wv] = sx[l]; s_wy[wv] = sy[l]; s_wz[wv] = sz[l];
        }
        __syncthreads();   // S1

        const int par = t & 1;
        unsigned long long* sgrp = ws + (size_t)((par * BATCH + b) * M) * SLOT_STRIDE;
        const unsigned int tt = (unsigned int)t;

        if (tid == 0) {
            unsigned long long kb = s_wkey[0];
            float bx = s_wx[0], by = s_wy[0], bz = s_wz[0];
#pragma unroll
            for (int i = 1; i < T / 64; ++i) {
                if (s_wkey[i] > kb) { kb = s_wkey[i]; bx = s_wx[i]; by = s_wy[i]; bz = s_wz[i]; }
            }
            unsigned int lidx = ~((unsigned int)kb);
            unsigned int g = (unsigned int)base + lidx;
            unsigned int db = (unsigned int)(kb >> 32);
            unsigned long long* sme = sgrp + (size_t)w * SLOT_STRIDE;
            unsigned long long tagHi = ((unsigned long long)tt) << 32;
            // self-tagged payload words; all relaxed — every word validates itself
            __hip_atomic_store(&sme[1], tagHi | __float_as_uint(bz),
                               __ATOMIC_RELAXED, __HIP_MEMORY_SCOPE_AGENT);
            __hip_atomic_store(&sme[2], tagHi | __float_as_uint(bx),
                               __ATOMIC_RELAXED, __HIP_MEMORY_SCOPE_AGENT);
            __hip_atomic_store(&sme[3], tagHi | __float_as_uint(by),
                               __ATOMIC_RELAXED, __HIP_MEMORY_SCOPE_AGENT);
            unsigned long long ka = ((unsigned long long)db << 32) |
                                    ((unsigned long long)(0xFFFFu - g) << 16) |
                                    (unsigned long long)tt;
            __hip_atomic_store(&sme[0], ka, __ATOMIC_RELAXED, __HIP_MEMORY_SCOPE_AGENT);
        }

        // ---- spin-exchange: lanes 0..15 watch one padded line each; key and
        // payload load in the SAME poll round -> one visibility hop typical ----
        if (tid < M) {
            unsigned long long* sp = sgrp + (size_t)tid * SLOT_STRIDE;
            unsigned long long k, zt, xt, yt;
            for (;;) {
                k  = __hip_atomic_load(&sp[0], __ATOMIC_ACQUIRE, __HIP_MEMORY_SCOPE_AGENT);
                zt = __hip_atomic_load(&sp[1], __ATOMIC_RELAXED, __HIP_MEMORY_SCOPE_AGENT);
                xt = __hip_atomic_load(&sp[2], __ATOMIC_RELAXED, __HIP_MEMORY_SCOPE_AGENT);
                yt = __hip_atomic_load(&sp[3], __ATOMIC_RELAXED, __HIP_MEMORY_SCOPE_AGENT);
                if ((unsigned short)k == (unsigned short)t) break;
            }
            unsigned long long kr = k;
#pragma unroll
            for (int off = 8; off >= 1; off >>= 1) {
                unsigned long long k2 = __shfl_down(kr, (unsigned)off, 64);
                kr = (k2 > kr) ? k2 : kr;
            }
            kr = __shfl(kr, 0, 64);                       // broadcast winner key
            unsigned int g = 0xFFFFu - (unsigned int)((kr >> 16) & 0xFFFFu);
            int ww = (int)(g >> 12);                      // winner WG (PTS=4096)
            unsigned long long zw = __shfl(zt, ww, 64);   // pull winner's payload
            unsigned long long xw = __shfl(xt, ww, 64);
            unsigned long long yw = __shfl(yt, ww, 64);
            if (tid == 0) {
                if ((unsigned int)(zw >> 32) != tt || (unsigned int)(xw >> 32) != tt ||
                    (unsigned int)(yw >> 32) != tt) {
                    // rare path: payload landed after key — acquire-spin re-read
                    unsigned long long* sw = sgrp + (size_t)ww * SLOT_STRIDE;
                    do { zw = __hip_atomic_load(&sw[1], __ATOMIC_ACQUIRE, __HIP_MEMORY_SCOPE_AGENT);
                    } while ((unsigned int)(zw >> 32) != tt);
                    do { xw = __hip_atomic_load(&sw[2], __ATOMIC_ACQUIRE, __HIP_MEMORY_SCOPE_AGENT);
                    } while ((unsigned int)(xw >> 32) != tt);
                    do { yw = __hip_atomic_load(&sw[3], __ATOMIC_ACQUIRE, __HIP_MEMORY_SCOPE_AGENT);
                    } while ((unsigned int)(yw >> 32) != tt);
                }
                s_qx = __uint_as_float((unsigned int)xw);
                s_qy = __uint_as_float((unsigned int)yw);
                s_qz = __uint_as_float((unsigned int)zw);
                if (w == 0) out[OUT_INDS + b * NPROP + t] = (float)g;
            }
        }
        __syncthreads();   // S2
        qx = s_qx; qy = s_qy; qz = s_qz;
    }
}

__global__ __launch_bounds__(256) void gather_kernel(const float* __restrict__ xyz,
                                                     const float* __restrict__ feat,
                                                     float* __restrict__ out) {
    int gid = blockIdx.x * 256 + threadIdx.x;   // covers B*C*N = 1,048,576
    int n = gid & (NPROP - 1);
    int b = gid >> 17;                          // C*N = 2^17
    int c = (gid >> 10) & (CFEAT - 1);
    int ind = (int)out[OUT_INDS + (b << 10) + n];   // float inds, exact < 2^24
    out[OUT_FEAT + gid] = feat[(((size_t)b * CFEAT + c) << 16) + (size_t)ind];
    if (gid < BATCH * NPROP) {
        int b2 = gid >> 10;
        int ind2 = (int)out[OUT_INDS + gid];
        const float* s = xyz + ((size_t)b2 * K + (size_t)ind2) * 3;
        float a0 = s[0], a1 = s[1], a2 = s[2];
        out[gid * 3 + 0] = a0;
        out[gid * 3 + 1] = a1;
        out[gid * 3 + 2] = a2;
    }
}

extern "C" void kernel_launch(void* const* d_in, const int* in_sizes, int n_in,
                              void* d_out, int out_size, void* d_ws, size_t ws_size,
                              hipStream_t stream) {
    const float* xyz = (const float*)d_in[0];
    const float* feat = (const float*)d_in[1];
    float* out = (float*)d_out;
    unsigned long long* ws = (unsigned long long*)d_ws;

    hipLaunchKernelGGL(fps_init, dim3(WS_ULLS / 256), dim3(256), 0, stream, ws);
    hipLaunchKernelGGL(fps_kernel, dim3(BATCH * M), dim3(T), 0, stream,
                       xyz, out, ws);
    hipLaunchKernelGGL(gather_kernel, dim3(BATCH * CFEAT * NPROP / 256), dim3(256),
                       0, stream, xyz, feat, out);
}

// Round 3
// 2782.115 us; speedup vs baseline: 1.6016x; 1.4245x over previous
//
#include <hip/hip_runtime.h>
#include <stdint.h>

#define BATCH 8
#define K 65536
#define CFEAT 128
#define NPROP 1024
#define M 16            // workgroups per batch
#define T 256           // threads per WG
#define PTS (K / M)     // 4096 points per WG
#define PPT (PTS / T)   // 16 points per thread

// d_out layout (float32): new_xyz (B,N,3) | new_features (B,C,N) | inds (B,N) as float
#define OUT_FEAT (BATCH * NPROP * 3)                         // 24576
#define OUT_INDS (BATCH * NPROP * 3 + BATCH * CFEAT * NPROP) // 1073152

// ws layout: slot[2][BATCH][M] blocks, each padded to its OWN 64B cacheline
// (8 ulls). Within a block: [0]=key{dist|0xFFFF-g|tag}, [1]={tag<<32|z},
// [2]={tag<<32|x}, [3]={tag<<32|y}.
// ALL spin-path accesses are RELAXED: every word self-validates via its
// embedded iteration tag, so no acquire ordering is needed. Agent-scope
// acquire loads emit buffer_inv (full L1/L2 invalidate) on gfx950 — doing
// that inside a 128-WG spin loop thrashed L2 chip-wide (round-2 FETCH_SIZE
// 2.4x round-1 despite identical data). Relaxed agent loads still carry sc1
// (coherence-point read) so remote stores remain visible.
#define SLOT_STRIDE 8
#define WS_ULLS (2 * BATCH * M * SLOT_STRIDE)   // 2048 ulls = 16 KB

__global__ __launch_bounds__(256) void fps_init(unsigned long long* ws) {
    int i = blockIdx.x * 256 + threadIdx.x;
    if (i < WS_ULLS) ws[i] = 0ull;   // tag 0 never matches t in [1,1023]
}

__global__ __launch_bounds__(T) void fps_kernel(const float* __restrict__ xyz,
                                                float* __restrict__ out,
                                                unsigned long long* __restrict__ ws) {
    const int b = blockIdx.x & 7;   // batch's 16 WGs round-robin onto one XCD
    const int w = blockIdx.x >> 3;
    const int tid = threadIdx.x;
    const float* xb = xyz + (size_t)b * (K * 3);
    const int base = w * PTS;

    __shared__ float sx[PTS], sy[PTS], sz[PTS];   // 48 KB: winner-coord recovery
    __shared__ unsigned long long s_wkey[T / 64];
    __shared__ float s_wx[T / 64], s_wy[T / 64], s_wz[T / 64];
    __shared__ float s_qx, s_qy, s_qz;

    float px[PPT], py[PPT], pz[PPT], dist[PPT];
#pragma unroll
    for (int j = 0; j < PPT; ++j) {
        int l = j * T + tid;
        int g = base + l;
        px[j] = xb[3 * g];
        py[j] = xb[3 * g + 1];
        pz[j] = xb[3 * g + 2];
        sx[l] = px[j]; sy[l] = py[j]; sz[l] = pz[j];
        dist[j] = 1e10f;
    }
    float qx = xb[0], qy = xb[1], qz = xb[2];
    if (w == 0 && tid == 0) out[OUT_INDS + b * NPROP] = 0.0f;
    __syncthreads();

    for (int t = 1; t < NPROP; ++t) {
        // ---- local distance update + per-thread argmax (bit-exact vs numpy:
        // no FMA contraction, (dx2+dy2)+dz2 order, first-max tie-break) ----
        unsigned long long best = 0ull;
#pragma unroll
        for (int j = 0; j < PPT; ++j) {
            float dx = __fsub_rn(px[j], qx);
            float dy = __fsub_rn(py[j], qy);
            float dz = __fsub_rn(pz[j], qz);
            float d = __fadd_rn(__fadd_rn(__fmul_rn(dx, dx), __fmul_rn(dy, dy)),
                                __fmul_rn(dz, dz));
            float nd = fminf(dist[j], d);
            dist[j] = nd;
            unsigned int l = (unsigned int)(j * T + tid);
            unsigned long long key =
                ((unsigned long long)__float_as_uint(nd) << 32) | (unsigned int)(~l);
            best = (key > best) ? key : best;
        }
#pragma unroll
        for (int off = 32; off >= 1; off >>= 1) {
            unsigned long long o = __shfl_down(best, (unsigned)off, 64);
            best = (o > best) ? o : best;
        }
        int wv = tid >> 6;
        if ((tid & 63) == 0) {
            unsigned int l = ~((unsigned int)best);
            s_wkey[wv] = best;
            s_wx[wv] = sx[l]; s_wy[wv] = sy[l]; s_wz[wv] = sz[l];
        }
        __syncthreads();   // S1

        const int par = t & 1;
        unsigned long long* sgrp = ws + (size_t)((par * BATCH + b) * M) * SLOT_STRIDE;
        const unsigned int tt = (unsigned int)t;

        if (tid == 0) {
            unsigned long long kb = s_wkey[0];
            float bx = s_wx[0], by = s_wy[0], bz = s_wz[0];
#pragma unroll
            for (int i = 1; i < T / 64; ++i) {
                if (s_wkey[i] > kb) { kb = s_wkey[i]; bx = s_wx[i]; by = s_wy[i]; bz = s_wz[i]; }
            }
            unsigned int lidx = ~((unsigned int)kb);
            unsigned int g = (unsigned int)base + lidx;
            unsigned int db = (unsigned int)(kb >> 32);
            unsigned long long* sme = sgrp + (size_t)w * SLOT_STRIDE;
            unsigned long long tagHi = ((unsigned long long)tt) << 32;
            // self-tagged words; all relaxed — every word validates itself
            __hip_atomic_store(&sme[1], tagHi | __float_as_uint(bz),
                               __ATOMIC_RELAXED, __HIP_MEMORY_SCOPE_AGENT);
            __hip_atomic_store(&sme[2], tagHi | __float_as_uint(bx),
                               __ATOMIC_RELAXED, __HIP_MEMORY_SCOPE_AGENT);
            __hip_atomic_store(&sme[3], tagHi | __float_as_uint(by),
                               __ATOMIC_RELAXED, __HIP_MEMORY_SCOPE_AGENT);
            unsigned long long ka = ((unsigned long long)db << 32) |
                                    ((unsigned long long)(0xFFFFu - g) << 16) |
                                    (unsigned long long)tt;
            __hip_atomic_store(&sme[0], ka, __ATOMIC_RELAXED, __HIP_MEMORY_SCOPE_AGENT);
        }

        // ---- spin-exchange: lanes 0..15 watch one padded line each; key and
        // payload load in the SAME poll round. Relaxed only: no buffer_inv. ----
        if (tid < M) {
            unsigned long long* sp = sgrp + (size_t)tid * SLOT_STRIDE;
            unsigned long long k, zt, xt, yt;
            for (;;) {
                k  = __hip_atomic_load(&sp[0], __ATOMIC_RELAXED, __HIP_MEMORY_SCOPE_AGENT);
                zt = __hip_atomic_load(&sp[1], __ATOMIC_RELAXED, __HIP_MEMORY_SCOPE_AGENT);
                xt = __hip_atomic_load(&sp[2], __ATOMIC_RELAXED, __HIP_MEMORY_SCOPE_AGENT);
                yt = __hip_atomic_load(&sp[3], __ATOMIC_RELAXED, __HIP_MEMORY_SCOPE_AGENT);
                if ((unsigned short)k == (unsigned short)t) break;
            }
            unsigned long long kr = k;
#pragma unroll
            for (int off = 8; off >= 1; off >>= 1) {
                unsigned long long k2 = __shfl_down(kr, (unsigned)off, 64);
                kr = (k2 > kr) ? k2 : kr;
            }
            kr = __shfl(kr, 0, 64);                       // broadcast winner key
            unsigned int g = 0xFFFFu - (unsigned int)((kr >> 16) & 0xFFFFu);
            int ww = (int)(g >> 12);                      // winner WG (PTS=4096)
            unsigned long long zw = __shfl(zt, ww, 64);   // pull winner's payload
            unsigned long long xw = __shfl(xt, ww, 64);
            unsigned long long yw = __shfl(yt, ww, 64);
            if (tid == 0) {
                if ((unsigned int)(zw >> 32) != tt || (unsigned int)(xw >> 32) != tt ||
                    (unsigned int)(yw >> 32) != tt) {
                    // rare path: payload landed after key — relaxed re-read,
                    // each word self-validates via its tag
                    unsigned long long* sw = sgrp + (size_t)ww * SLOT_STRIDE;
                    do { zw = __hip_atomic_load(&sw[1], __ATOMIC_RELAXED, __HIP_MEMORY_SCOPE_AGENT);
                    } while ((unsigned int)(zw >> 32) != tt);
                    do { xw = __hip_atomic_load(&sw[2], __ATOMIC_RELAXED, __HIP_MEMORY_SCOPE_AGENT);
                    } while ((unsigned int)(xw >> 32) != tt);
                    do { yw = __hip_atomic_load(&sw[3], __ATOMIC_RELAXED, __HIP_MEMORY_SCOPE_AGENT);
                    } while ((unsigned int)(yw >> 32) != tt);
                }
                s_qx = __uint_as_float((unsigned int)xw);
                s_qy = __uint_as_float((unsigned int)yw);
                s_qz = __uint_as_float((unsigned int)zw);
                if (w == 0) out[OUT_INDS + b * NPROP + t] = (float)g;
            }
        }
        __syncthreads();   // S2
        qx = s_qx; qy = s_qy; qz = s_qz;
    }
}

__global__ __launch_bounds__(256) void gather_kernel(const float* __restrict__ xyz,
                                                     const float* __restrict__ feat,
                                                     float* __restrict__ out) {
    int gid = blockIdx.x * 256 + threadIdx.x;   // covers B*C*N = 1,048,576
    int n = gid & (NPROP - 1);
    int b = gid >> 17;                          // C*N = 2^17
    int c = (gid >> 10) & (CFEAT - 1);
    int ind = (int)out[OUT_INDS + (b << 10) + n];   // float inds, exact < 2^24
    out[OUT_FEAT + gid] = feat[(((size_t)b * CFEAT + c) << 16) + (size_t)ind];
    if (gid < BATCH * NPROP) {
        int b2 = gid >> 10;
        int ind2 = (int)out[OUT_INDS + gid];
        const float* s = xyz + ((size_t)b2 * K + (size_t)ind2) * 3;
        float a0 = s[0], a1 = s[1], a2 = s[2];
        out[gid * 3 + 0] = a0;
        out[gid * 3 + 1] = a1;
        out[gid * 3 + 2] = a2;
    }
}

extern "C" void kernel_launch(void* const* d_in, const int* in_sizes, int n_in,
                              void* d_out, int out_size, void* d_ws, size_t ws_size,
                              hipStream_t stream) {
    const float* xyz = (const float*)d_in[0];
    const float* feat = (const float*)d_in[1];
    float* out = (float*)d_out;
    unsigned long long* ws = (unsigned long long*)d_ws;

    hipLaunchKernelGGL(fps_init, dim3(WS_ULLS / 256), dim3(256), 0, stream, ws);
    hipLaunchKernelGGL(fps_kernel, dim3(BATCH * M), dim3(T), 0, stream,
                       xyz, out, ws);
    hipLaunchKernelGGL(gather_kernel, dim3(BATCH * CFEAT * NPROP / 256), dim3(256),
                       0, stream, xyz, feat, out);
}